// Round 13
// baseline (240.397 us; speedup 1.0000x reference)
//
#include <hip/hip_runtime.h>
#include <stdint.h>

#define CDIM 256
#define HW 2304
#define FR 3
#define NBATCH 2
#define NTOK 6912
#define EPSV 1e-6f
#define QSCALE (0.0625f * 1.44269504088896f)

typedef __attribute__((ext_vector_type(8))) short short8;
typedef __attribute__((ext_vector_type(4))) short short4v;
typedef __attribute__((ext_vector_type(4))) float f32x4;
typedef __attribute__((ext_vector_type(16))) float f32x16;
typedef __attribute__((ext_vector_type(4))) uint32_t u32x4;
typedef unsigned short u16;

__device__ inline u16 f2bf(float f) {
  union { float f; uint32_t u; } v; v.f = f;
  uint32_t r = v.u + 0x7FFFu + ((v.u >> 16) & 1u);
  return (u16)(r >> 16);
}
__device__ inline float bf2f(u16 h) {
  union { uint32_t u; float f; } v; v.u = ((uint32_t)h) << 16; return v.f;
}
__device__ inline void gload16(const void* g, void* l) {
  __builtin_amdgcn_global_load_lds(
      (const __attribute__((address_space(1))) void*)g,
      (__attribute__((address_space(3))) void*)l, 16, 0, 0);
}

// ------------- kernel 1: weight cvt (blocks 256..511) + GN partials ---------
__global__ void pre_k(const float* x, float* part, const float* wq,
                      const float* wk, const float* wv, const float* wp,
                      u16* wb) {
  if (blockIdx.x >= 256) {
    int idx = (blockIdx.x - 256) * 256 + threadIdx.x;
    wb[0 * 65536 + idx] = f2bf(wq[idx] * QSCALE);
    wb[1 * 65536 + idx] = f2bf(wk[idx]);
    wb[2 * 65536 + idx] = f2bf(wv[idx]);
    wb[3 * 65536 + idx] = f2bf(wp[idx]);
    return;
  }
  int bg = blockIdx.x >> 5, sl = blockIdx.x & 31;
  int b = bg >> 2, g = bg & 3;
  int tid = threadIdx.x;
  float s1 = 0.f, s2 = 0.f;
  for (int i = tid; i < 2 * NTOK; i += 256) {
    int cl = sl * 2 + (i / NTOK); int rem = i % NTOK;
    int f = rem / HW; int hw = rem - f * HW;
    float v = x[((size_t)(f * NBATCH + b) * CDIM + g * 64 + cl) * HW + hw];
    s1 += v; s2 += v * v;
  }
  #pragma unroll
  for (int m = 32; m >= 1; m >>= 1) {
    s1 += __shfl_xor(s1, m, 64);
    s2 += __shfl_xor(s2, m, 64);
  }
  __shared__ float r1[4], r2[4];
  int wid = tid >> 6;
  if ((tid & 63) == 0) { r1[wid] = s1; r2[wid] = s2; }
  __syncthreads();
  if (tid == 0) {
    part[blockIdx.x * 2 + 0] = r1[0] + r1[1] + r1[2] + r1[3];
    part[blockIdx.x * 2 + 1] = r2[0] + r2[1] + r2[2] + r2[3];
  }
}

// ------------- kernel 2: fused GN-normalize/transpose + single-op GEMM ------
// Grid (108 nt, 6 = op*2+b): each block finalizes stats inline, normalizes
// + transposes its x tile into swizzled bf16 LDS, then runs ONE GEMM.
// q: D[co][n] (swapped mfma) -> qb[b][n][co]
// k: D[co][n] (swapped)      -> kb[b][tile][colchunk32][row64][8elem]
// v: D[n][co] (normal)       -> vb[b][tile][mchunk8][c256][8elem]
__global__ __launch_bounds__(256) void qkvx_k(const float* x, const float* part,
    const float* gn_w, const float* gn_b, const u16* wb,
    const float* bq, const float* bk, const float* bv,
    u16* qb, u16* kb, u16* vb) {
  int nt = blockIdx.x;
  int op = blockIdx.y >> 1, b = blockIdx.y & 1;
  int tid = threadIdx.x, lane = tid & 63, wid = tid >> 6;
  int lr = lane & 15, lg = lane >> 4;
  __shared__ __align__(16) char hn_lds[32768];   // [64 n][256 c] bf16 swizzled
  __shared__ float tile[64][65];
  __shared__ float sstat[8];

  // finalize GN stats for this b: 4 groups x 32 slice-partials
  if (tid < 128) {
    int g = (tid >> 5) & 3, s = tid & 31;
    int gi = (tid >> 6) * 2 + ((tid >> 5) & 1);   // g = wave*2 + half
    g = gi;
    float p1 = part[((b * 4 + g) * 32 + s) * 2 + 0];
    float p2 = part[((b * 4 + g) * 32 + s) * 2 + 1];
    #pragma unroll
    for (int m = 1; m < 32; m <<= 1) {
      p1 += __shfl_xor(p1, m, 32);
      p2 += __shfl_xor(p2, m, 32);
    }
    if (s == 0) {
      float inv = 1.f / (64.f * NTOK);
      float mu = p1 * inv;
      float var = p2 * inv - mu * mu;
      sstat[g * 2 + 0] = mu;
      sstat[g * 2 + 1] = rsqrtf(var + EPSV);
    }
  }
  __syncthreads();

  // normalize + transpose x -> hn_lds (4 chunks of 64 channels)
  int n0 = nt * 64; int f = n0 / HW; int hw0 = n0 - f * HW;
  #pragma unroll
  for (int ct = 0; ct < 4; ++ct) {
    float mu = sstat[ct * 2 + 0];
    float rs = sstat[ct * 2 + 1];
    #pragma unroll
    for (int i = 0; i < 16; ++i) {
      int lin = i * 256 + tid;
      int cr = lin >> 6, nc = lin & 63;
      int c = ct * 64 + cr;
      float v = x[((size_t)(f * NBATCH + b) * CDIM + c) * HW + hw0 + nc];
      tile[cr][nc] = (v - mu) * rs * gn_w[c] + gn_b[c];
    }
    __syncthreads();
    #pragma unroll
    for (int i = 0; i < 8; ++i) {
      int lin = i * 256 + tid;         // 2048 = 64 n x 32 c-pairs
      int nr = lin >> 5, cp = lin & 31;
      int cc = cp * 2;
      uint32_t pk = (uint32_t)f2bf(tile[cc][nr]) |
                    ((uint32_t)f2bf(tile[cc + 1][nr]) << 16);
      int byte = nr * 512 + (ct * 64 + cc) * 2;
      *(uint32_t*)(hn_lds + (byte ^ ((nr & 7) << 4))) = pk;
    }
    __syncthreads();
  }

  // single GEMM for this op
  f32x4 acc[16];
  #pragma unroll
  for (int i = 0; i < 16; ++i) acc[i] = (f32x4){0.f, 0.f, 0.f, 0.f};
  const u16* wsrc = wb + op * 65536;
  __builtin_amdgcn_s_setprio(1);
  #pragma unroll
  for (int cc = 0; cc < 4; ++cc) {
    short8 afr[2];
    #pragma unroll
    for (int kc = 0; kc < 2; ++kc) {
      int row = wid * 16 + lr;
      int byte = row * 512 + (cc * 64 + kc * 32 + lg * 8) * 2;
      afr[kc] = *(const short8*)(hn_lds + (byte ^ ((row & 7) << 4)));
    }
    #pragma unroll
    for (int cot = 0; cot < 16; ++cot) {
      #pragma unroll
      for (int kc = 0; kc < 2; ++kc) {
        short8 bfr = *(const short8*)(wsrc + (size_t)(cot * 16 + lr) * CDIM +
                                      cc * 64 + kc * 32 + lg * 8);
        if (op == 2)
          acc[cot] = __builtin_amdgcn_mfma_f32_16x16x32_bf16(afr[kc], bfr, acc[cot], 0, 0, 0);
        else
          acc[cot] = __builtin_amdgcn_mfma_f32_16x16x32_bf16(bfr, afr[kc], acc[cot], 0, 0, 0);
      }
    }
  }
  __builtin_amdgcn_s_setprio(0);
  if (op == 2) {
    int m0 = wid * 16 + lg * 4;
    char* vtile = (char*)vb + (size_t)b * NTOK * CDIM * 2 + (size_t)nt * 32768;
    int mchunk = (m0 >> 3);
    #pragma unroll
    for (int cot = 0; cot < 16; ++cot) {
      int co = cot * 16 + lr;
      float bb = bv[co];
      short4v r;
      #pragma unroll
      for (int j = 0; j < 4; ++j) r[j] = (short)f2bf(acc[cot][j] + bb);
      *(short4v*)(vtile + mchunk * 4096 + co * 16 + (lg & 1) * 8) = r;
    }
  } else {
    int row = wid * 16 + lr;
    int n = nt * 64 + row;
    const float* bias = (op == 0) ? bq : bk;
    float bscale = (op == 0) ? QSCALE : 1.0f;
    char* ktile = (char*)kb + (size_t)b * NTOK * CDIM * 2 + (size_t)nt * 32768;
    #pragma unroll
    for (int cot = 0; cot < 16; ++cot) {
      int co = cot * 16 + lg * 4;
      f32x4 b4 = *(const f32x4*)(bias + co);
      short4v r;
      #pragma unroll
      for (int j = 0; j < 4; ++j) r[j] = (short)f2bf(acc[cot][j] + b4[j] * bscale);
      if (op == 0) {
        *(short4v*)(qb + ((size_t)b * NTOK + n) * CDIM + co) = r;
      } else {
        int colchunk = cot * 2 + (lg >> 1);
        *(short4v*)(ktile + colchunk * 1024 + row * 16 + (lg & 1) * 8) = r;
      }
    }
  }
}

// ------------- kernel 3: flash attention (exact round-8 structure) ----------
// 512 threads = 8 waves x 32 q-cols; lane owns column n = q0 + (lane&31).
// QK^T: S = mfma_32x32x16(K, Q); softmax lane-local; P via cvt_pk +
// permlane32_swap (no LDS P). K,V double-buffered LDS, immediate-offset
// layouts, linear gload_lds staging.
template <bool SPLIT>
__global__ __launch_bounds__(512, 2) void flash_k(const u16* qb, const u16* kb,
                                                  const u16* vb, u16* opart,
                                                  float* ml, u16* ob) {
  int qt = blockIdx.x, b = blockIdx.y, sp = blockIdx.z;
  int tid = threadIdx.x, lane = tid & 63, wid = tid >> 6;
  int ln = lane & 31, hi = lane >> 5;
  __shared__ __align__(16) char k_lds[2][32768];   // [kc 32][m 64][16B]
  __shared__ __align__(16) char v_lds[2][32768];   // [mc 8][c 256][16B]

  int t0 = SPLIT ? 27 * sp : 0;
  int t1 = SPLIT ? 27 * sp + 27 : 108;

  int nq = qt * 256 + wid * 32 + ln;
  const u16* qsrc = qb + ((size_t)b * NTOK + nq) * CDIM;
  short8 qf[16];
  #pragma unroll
  for (int ks = 0; ks < 16; ++ks)
    qf[ks] = *(const short8*)(qsrc + ks * 16 + hi * 8);

  float mrun = -1e30f, lrun = 0.f;
  f32x16 o[8];
  #pragma unroll
  for (int i = 0; i < 8; ++i)
    #pragma unroll
    for (int j = 0; j < 16; ++j) o[i][j] = 0.f;

  const char* kbb = (const char*)(kb + (size_t)b * NTOK * CDIM);
  const char* vbb = (const char*)(vb + (size_t)b * NTOK * CDIM);
  int kbase = hi * 1024 + ln * 16;
  int vbase = hi * 4096 + ln * 16;

  {  // prologue: stage tile t0 into buf 0 (64 x 1KB chunks over 8 waves)
    const char* ks_ = kbb + (size_t)t0 * 32768;
    const char* vs_ = vbb + (size_t)t0 * 32768;
    #pragma unroll
    for (int i = 0; i < 8; ++i) {
      int ch = i * 8 + wid;
      if (ch < 32) gload16(ks_ + ch * 1024 + lane * 16, k_lds[0] + ch * 1024);
      else gload16(vs_ + (ch - 32) * 1024 + lane * 16, v_lds[0] + (ch - 32) * 1024);
    }
  }
  __syncthreads();

  for (int t = t0; t < t1; ++t) {
    int cur = (t - t0) & 1;
    if (t + 1 < t1) {  // prefetch next tile into other buffers
      const char* ks_ = kbb + (size_t)(t + 1) * 32768;
      const char* vs_ = vbb + (size_t)(t + 1) * 32768;
      #pragma unroll
      for (int i = 0; i < 8; ++i) {
        int ch = i * 8 + wid;
        if (ch < 32) gload16(ks_ + ch * 1024 + lane * 16, k_lds[cur ^ 1] + ch * 1024);
        else gload16(vs_ + (ch - 32) * 1024 + lane * 16, v_lds[cur ^ 1] + (ch - 32) * 1024);
      }
    }
    const char* kc = k_lds[cur] + kbase;
    const char* vc = v_lds[cur] + vbase;

    #pragma unroll
    for (int mt = 0; mt < 2; ++mt) {
      // QK^T m-tile: S[m = mt*32 + (r&3)+8*(r>>2)+4*hi][n = lane&31]
      f32x16 S;
      #pragma unroll
      for (int j = 0; j < 16; ++j) S[j] = 0.f;
      __builtin_amdgcn_s_setprio(1);
      #pragma unroll
      for (int ks = 0; ks < 16; ++ks) {
        short8 kf = *(const short8*)(kc + ks * 2048 + mt * 512);
        S = __builtin_amdgcn_mfma_f32_32x32x16_bf16(kf, qf[ks], S, 0, 0, 0);
      }
      __builtin_amdgcn_s_setprio(0);
      // column max: own 16 rows + partner (lane^32)
      float px = S[0];
      #pragma unroll
      for (int j = 1; j < 16; ++j) px = fmaxf(px, S[j]);
      px = fmaxf(px, __shfl_xor(px, 32, 64));
      if (__any(px > mrun + 10.0f)) {   // defer-max; rare after first tile
        float mn = fmaxf(mrun, px);
        float r = exp2f(mrun - mn);
        mrun = mn; lrun *= r;
        #pragma unroll
        for (int i = 0; i < 8; ++i)
          #pragma unroll
          for (int j = 0; j < 16; ++j) o[i][j] *= r;
      }
      float lsum = 0.f;
      #pragma unroll
      for (int j = 0; j < 16; ++j) {
        float p = exp2f(S[j] - mrun);
        S[j] = p; lsum += p;
      }
      lsum += __shfl_xor(lsum, 32, 64);
      lrun += lsum;
      // P pack + PV per local k-step (m = mt*32 + lks*16 + ..)
      #pragma unroll
      for (int lks = 0; lks < 2; ++lks) {
        int rb = lks * 8;
        uint32_t x0, x1, y0, y1;
        asm("v_cvt_pk_bf16_f32 %0, %1, %2" : "=v"(x0) : "v"(S[rb + 0]), "v"(S[rb + 1]));
        asm("v_cvt_pk_bf16_f32 %0, %1, %2" : "=v"(x1) : "v"(S[rb + 2]), "v"(S[rb + 3]));
        asm("v_cvt_pk_bf16_f32 %0, %1, %2" : "=v"(y0) : "v"(S[rb + 4]), "v"(S[rb + 5]));
        asm("v_cvt_pk_bf16_f32 %0, %1, %2" : "=v"(y1) : "v"(S[rb + 6]), "v"(S[rb + 7]));
        // swap vdst upper32 lanes <-> src0 lower32: x' = frag dw0, y' = frag dw2
        asm("v_permlane32_swap_b32 %0, %1" : "+v"(x0), "+v"(y0));
        asm("v_permlane32_swap_b32 %0, %1" : "+v"(x1), "+v"(y1));
        u32x4 pd = (u32x4){x0, x1, y0, y1};
        short8 pf = *(short8*)&pd;
        __builtin_amdgcn_s_setprio(1);
        #pragma unroll
        for (int ct = 0; ct < 8; ++ct) {
          short8 vf = *(const short8*)(vc + (mt * 2 + lks) * 8192 + ct * 512);
          o[ct] = __builtin_amdgcn_mfma_f32_32x32x16_bf16(vf, pf, o[ct], 0, 0, 0);
        }
        __builtin_amdgcn_s_setprio(0);
      }
    }
    __syncthreads();
  }

  // epilogue: lane col n fixed; c = ct*32 + (r&3)+8*(r>>2)+4*hi -> 8B stores
  if (!SPLIT) {
    float linv = 1.0f / lrun;
    u16* d0 = ob + ((size_t)b * NTOK + nq) * CDIM;
    #pragma unroll
    for (int ct = 0; ct < 8; ++ct) {
      #pragma unroll
      for (int rq = 0; rq < 4; ++rq) {
        short4v r4;
        #pragma unroll
        for (int j = 0; j < 4; ++j) r4[j] = (short)f2bf(o[ct][rq * 4 + j] * linv);
        *(short4v*)(d0 + ct * 32 + rq * 8 + hi * 4) = r4;
      }
    }
  } else {
    u16* d0 = opart + ((size_t)(sp * 2 + b) * NTOK + nq) * CDIM;
    #pragma unroll
    for (int ct = 0; ct < 8; ++ct) {
      #pragma unroll
      for (int rq = 0; rq < 4; ++rq) {
        short4v r4;
        #pragma unroll
        for (int j = 0; j < 4; ++j) r4[j] = (short)f2bf(o[ct][rq * 4 + j]);
        *(short4v*)(d0 + ct * 32 + rq * 8 + hi * 4) = r4;
      }
    }
    if (hi == 0) {
      size_t mb = (size_t)(sp * 2 + b) * 2;
      ml[(mb + 0) * NTOK + nq] = mrun;
      ml[(mb + 1) * NTOK + nq] = lrun;
    }
  }
}

// ------------- kernel 4: [combine 4 partials +] proj_out + residual ---------
template <bool SPLIT>
__global__ __launch_bounds__(256) void proj_k(const u16* ob, const u16* opart,
    const float* ml, const u16* wb, const float* bp, const float* x, float* out) {
  int nt = blockIdx.x, b = blockIdx.y;
  int tid = threadIdx.x, lane = tid & 63, wid = tid >> 6;
  int lr = lane & 15, lg = lane >> 4;
  __shared__ __align__(16) char o_lds[32768];   // [64 n][256 c] swizzled
  const u16* wpb = wb + 3 * 65536;
  if (SPLIT) {
    #pragma unroll
    for (int i = 0; i < 8; ++i) {
      int off = i * 4096 + tid * 16;
      int row = off >> 9;
      int c0 = (off & 511) >> 1;
      int n = nt * 64 + row;
      float mm[4], llv[4];
      #pragma unroll
      for (int s = 0; s < 4; ++s) {
        mm[s] = ml[((size_t)(s * 2 + b) * 2 + 0) * NTOK + n];
        llv[s] = ml[((size_t)(s * 2 + b) * 2 + 1) * NTOK + n];
      }
      float M = fmaxf(fmaxf(mm[0], mm[1]), fmaxf(mm[2], mm[3]));
      float w[4]; float den = 0.f;
      #pragma unroll
      for (int s = 0; s < 4; ++s) { w[s] = exp2f(mm[s] - M); den += w[s] * llv[s]; }
      float inv = 1.f / den;
      float o[8] = {0.f, 0.f, 0.f, 0.f, 0.f, 0.f, 0.f, 0.f};
      #pragma unroll
      for (int s = 0; s < 4; ++s) {
        short8 v = *(const short8*)(opart + ((size_t)(s * 2 + b) * NTOK + n) * CDIM + c0);
        #pragma unroll
        for (int j = 0; j < 8; ++j) o[j] += w[s] * bf2f((u16)v[j]);
      }
      short8 r8;
      #pragma unroll
      for (int j = 0; j < 8; ++j) r8[j] = (short)f2bf(o[j] * inv);
      *(short8*)(o_lds + (off ^ ((row & 7) << 4))) = r8;
    }
  } else {
    const char* src = (const char*)(ob + ((size_t)b * NTOK + nt * 64) * CDIM);
    #pragma unroll
    for (int i = 0; i < 8; ++i) {
      int off = i * 4096 + wid * 1024 + lane * 16;
      int row = off >> 9;
      gload16(src + (off ^ ((row & 7) << 4)), o_lds + i * 4096 + wid * 1024);
    }
  }
  __syncthreads();
  #pragma unroll
  for (int ct2 = 0; ct2 < 4; ++ct2) {
    int cot = wid * 4 + ct2;
    short8 aw[8];
    #pragma unroll
    for (int kc = 0; kc < 8; ++kc)
      aw[kc] = *(const short8*)(wpb + (size_t)(cot * 16 + lr) * CDIM + kc * 32 + lg * 8);
    #pragma unroll
    for (int ntile = 0; ntile < 4; ++ntile) {
      f32x4 a = (f32x4){0.f, 0.f, 0.f, 0.f};
      #pragma unroll
      for (int kc = 0; kc < 8; ++kc) {
        int row = ntile * 16 + lr;
        int byte = row * 512 + (kc * 32 + lg * 8) * 2;
        short8 bfr = *(const short8*)(o_lds + (byte ^ ((row & 7) << 4)));
        a = __builtin_amdgcn_mfma_f32_16x16x32_bf16(aw[kc], bfr, a, 0, 0, 0);
      }
      int n = nt * 64 + ntile * 16 + lr;
      int f = n / HW; int hw = n - f * HW;
      #pragma unroll
      for (int j = 0; j < 4; ++j) {
        int co = cot * 16 + lg * 4 + j;
        float val = a[j] + bp[co];
        size_t oi = ((size_t)(b * FR + f) * CDIM + co) * HW + hw;
        out[oi] = x[oi] + val;
      }
    }
  }
}

extern "C" void kernel_launch(void* const* d_in, const int* in_sizes, int n_in,
                              void* d_out, int out_size, void* d_ws, size_t ws_size,
                              hipStream_t stream) {
  const float* x    = (const float*)d_in[0];
  const float* gn_w = (const float*)d_in[1];
  const float* gn_b = (const float*)d_in[2];
  const float* wq   = (const float*)d_in[3];
  const float* bq   = (const float*)d_in[4];
  const float* wk   = (const float*)d_in[5];
  const float* bk   = (const float*)d_in[6];
  const float* wv   = (const float*)d_in[7];
  const float* bv   = (const float*)d_in[8];
  const float* wp   = (const float*)d_in[9];
  const float* bp   = (const float*)d_in[10];
  float* out = (float*)d_out;
  char* ws = (char*)d_ws;

  float* part  = (float*)(ws + 256);        // 512 f32
  u16* wb = (u16*)(ws + 4096);              // 4*256*256
  u16* qb = (u16*)(ws + 7606272);
  u16* kb = (u16*)(ws + 14684160);          // [b][tile][colchunk][row][8]
  u16* vb = (u16*)(ws + 21762048);          // [b][tile][mchunk][c][8]
  u16* ob = (u16*)(ws + 28839936);
  u16* opart = (u16*)(ws + 35917824);       // [4 sp][2 b][6912 n][256 c] bf16
  float* ml  = (float*)(ws + 64229376);     // [4 sp][2 b][2][6912] f32
  const size_t NEED_SPLIT = 64671744;

  pre_k<<<512, 256, 0, stream>>>(x, part, wq, wk, wv, wp, wb);
  qkvx_k<<<dim3(108, 6), 256, 0, stream>>>(x, part, gn_w, gn_b, wb,
                                           bq, bk, bv, qb, kb, vb);
  if (ws_size >= NEED_SPLIT) {
    flash_k<true><<<dim3(27, 2, 4), 512, 0, stream>>>(qb, kb, vb, opart, ml, ob);
    proj_k<true><<<dim3(108, 2), 256, 0, stream>>>(ob, opart, ml, wb, bp, x, out);
  } else {
    flash_k<false><<<dim3(27, 2, 1), 512, 0, stream>>>(qb, kb, vb, opart, ml, ob);
    proj_k<false><<<dim3(108, 2), 256, 0, stream>>>(ob, opart, ml, wb, bp, x, out);
  }
}

// Round 14
// 216.128 us; speedup vs baseline: 1.1123x; 1.1123x over previous
//
#include <hip/hip_runtime.h>
#include <stdint.h>

#define CDIM 256
#define HW 2304
#define FR 3
#define NBATCH 2
#define NTOK 6912
#define EPSV 1e-6f
#define QSCALE (0.0625f * 1.44269504088896f)

typedef __attribute__((ext_vector_type(8))) short short8;
typedef __attribute__((ext_vector_type(4))) short short4v;
typedef __attribute__((ext_vector_type(4))) float f32x4;
typedef __attribute__((ext_vector_type(16))) float f32x16;
typedef __attribute__((ext_vector_type(4))) uint32_t u32x4;
typedef unsigned short u16;

__device__ inline u16 f2bf(float f) {
  union { float f; uint32_t u; } v; v.f = f;
  uint32_t r = v.u + 0x7FFFu + ((v.u >> 16) & 1u);
  return (u16)(r >> 16);
}
__device__ inline float bf2f(u16 h) {
  union { uint32_t u; float f; } v; v.u = ((uint32_t)h) << 16; return v.f;
}
__device__ inline void gload16(const void* g, void* l) {
  __builtin_amdgcn_global_load_lds(
      (const __attribute__((address_space(1))) void*)g,
      (__attribute__((address_space(3))) void*)l, 16, 0, 0);
}

// ------------- kernel 1: weight cvt (blocks 256..511) + GN partials ---------
__global__ void pre_k(const float* x, float* part, const float* wq,
                      const float* wk, const float* wv, const float* wp,
                      u16* wb) {
  if (blockIdx.x >= 256) {
    int idx = (blockIdx.x - 256) * 256 + threadIdx.x;
    wb[0 * 65536 + idx] = f2bf(wq[idx] * QSCALE);
    wb[1 * 65536 + idx] = f2bf(wk[idx]);
    wb[2 * 65536 + idx] = f2bf(wv[idx]);
    wb[3 * 65536 + idx] = f2bf(wp[idx]);
    return;
  }
  int bg = blockIdx.x >> 5, sl = blockIdx.x & 31;
  int b = bg >> 2, g = bg & 3;
  int tid = threadIdx.x;
  float s1 = 0.f, s2 = 0.f;
  for (int i = tid; i < 2 * NTOK; i += 256) {
    int cl = sl * 2 + (i / NTOK); int rem = i % NTOK;
    int f = rem / HW; int hw = rem - f * HW;
    float v = x[((size_t)(f * NBATCH + b) * CDIM + g * 64 + cl) * HW + hw];
    s1 += v; s2 += v * v;
  }
  #pragma unroll
  for (int m = 32; m >= 1; m >>= 1) {
    s1 += __shfl_xor(s1, m, 64);
    s2 += __shfl_xor(s2, m, 64);
  }
  __shared__ float r1[4], r2[4];
  int wid = tid >> 6;
  if ((tid & 63) == 0) { r1[wid] = s1; r2[wid] = s2; }
  __syncthreads();
  if (tid == 0) {
    part[blockIdx.x * 2 + 0] = r1[0] + r1[1] + r1[2] + r1[3];
    part[blockIdx.x * 2 + 1] = r2[0] + r2[1] + r2[2] + r2[3];
  }
}

// ------------- kernel 2: finalize stats -------------------------------------
__global__ void gn_fin_k(const float* part, float* stats) {
  int tid = threadIdx.x;
  if (tid < 8) {
    float s1 = 0.f, s2 = 0.f;
    for (int s = 0; s < 32; ++s) {
      s1 += part[(tid * 32 + s) * 2 + 0];
      s2 += part[(tid * 32 + s) * 2 + 1];
    }
    float inv = 1.f / (64.f * NTOK);
    float mu = s1 * inv;
    float var = s2 * inv - mu * mu;
    stats[tid * 2 + 0] = mu;
    stats[tid * 2 + 1] = rsqrtf(var + EPSV);
  }
}

// ------------- kernel 3: normalize + transpose -> hn[b][n][c] bf16 ----------
__global__ void gn_apply_k(const float* x, const float* gn_w, const float* gn_b,
                           const float* stats, u16* hn) {
  int nt = blockIdx.x, ct = blockIdx.y, b = blockIdx.z;
  int tid = threadIdx.x;
  __shared__ float tile[64][65];
  int n0 = nt * 64; int f = n0 / HW; int hw0 = n0 - f * HW;
  float mu = stats[(b * 4 + ct) * 2 + 0];
  float rs = stats[(b * 4 + ct) * 2 + 1];
  #pragma unroll
  for (int i = 0; i < 16; ++i) {
    int lin = i * 256 + tid;
    int cr = lin >> 6, nc = lin & 63;
    int c = ct * 64 + cr;
    float v = x[((size_t)(f * NBATCH + b) * CDIM + c) * HW + hw0 + nc];
    tile[cr][nc] = (v - mu) * rs * gn_w[c] + gn_b[c];
  }
  __syncthreads();
  #pragma unroll
  for (int i = 0; i < 16; ++i) {
    int lin = i * 256 + tid;
    int nr = lin >> 6, cc = lin & 63;
    hn[((size_t)b * NTOK + n0 + nr) * CDIM + ct * 64 + cc] = f2bf(tile[cc][nr]);
  }
}

// ------------- kernel 4: QKV GEMM -------------------------------------------
// q: D[co][n] (swapped mfma) -> qb[b][n][co]
// k: D[co][n] (swapped)      -> kb[b][tile][colchunk32][row64][8elem]
// v: D[n][co] (normal)       -> vb[b][tile][mchunk8][c256][8elem]
__global__ __launch_bounds__(256) void qkv_k(const u16* hn, const u16* wb,
    const float* bq, const float* bk, const float* bv,
    u16* qb, u16* kb, u16* vb) {
  int nt = blockIdx.x;
  int op = blockIdx.y >> 1, b = blockIdx.y & 1;
  int tid = threadIdx.x, lane = tid & 63, wid = tid >> 6;
  int lr = lane & 15, lg = lane >> 4;
  __shared__ __align__(16) char hn_lds[32768];   // [64 n][256 c] swizzled
  {
    const char* src = (const char*)(hn + ((size_t)b * NTOK + nt * 64) * CDIM);
    #pragma unroll
    for (int i = 0; i < 8; ++i) {
      int off = i * 4096 + wid * 1024 + lane * 16;
      int row = off >> 9;
      gload16(src + (off ^ ((row & 7) << 4)), hn_lds + i * 4096 + wid * 1024);
    }
  }
  __syncthreads();
  f32x4 acc[16];
  #pragma unroll
  for (int i = 0; i < 16; ++i) acc[i] = (f32x4){0.f, 0.f, 0.f, 0.f};
  const u16* wsrc = wb + op * 65536;
  __builtin_amdgcn_s_setprio(1);
  #pragma unroll
  for (int cc = 0; cc < 4; ++cc) {
    short8 afr[2];
    #pragma unroll
    for (int kc = 0; kc < 2; ++kc) {
      int row = wid * 16 + lr;
      int byte = row * 512 + (cc * 64 + kc * 32 + lg * 8) * 2;
      afr[kc] = *(const short8*)(hn_lds + (byte ^ ((row & 7) << 4)));
    }
    #pragma unroll
    for (int cot = 0; cot < 16; ++cot) {
      #pragma unroll
      for (int kc = 0; kc < 2; ++kc) {
        short8 bfr = *(const short8*)(wsrc + (size_t)(cot * 16 + lr) * CDIM +
                                      cc * 64 + kc * 32 + lg * 8);
        if (op == 2)
          acc[cot] = __builtin_amdgcn_mfma_f32_16x16x32_bf16(afr[kc], bfr, acc[cot], 0, 0, 0);
        else
          acc[cot] = __builtin_amdgcn_mfma_f32_16x16x32_bf16(bfr, afr[kc], acc[cot], 0, 0, 0);
      }
    }
  }
  __builtin_amdgcn_s_setprio(0);
  if (op == 2) {
    int m0 = wid * 16 + lg * 4;
    char* vtile = (char*)vb + (size_t)b * NTOK * CDIM * 2 + (size_t)nt * 32768;
    int mchunk = (m0 >> 3);
    #pragma unroll
    for (int cot = 0; cot < 16; ++cot) {
      int co = cot * 16 + lr;
      float bb = bv[co];
      short4v r;
      #pragma unroll
      for (int j = 0; j < 4; ++j) r[j] = (short)f2bf(acc[cot][j] + bb);
      *(short4v*)(vtile + mchunk * 4096 + co * 16 + (lg & 1) * 8) = r;
    }
  } else {
    int row = wid * 16 + lr;
    int n = nt * 64 + row;
    const float* bias = (op == 0) ? bq : bk;
    float bscale = (op == 0) ? QSCALE : 1.0f;
    char* ktile = (char*)kb + (size_t)b * NTOK * CDIM * 2 + (size_t)nt * 32768;
    #pragma unroll
    for (int cot = 0; cot < 16; ++cot) {
      int co = cot * 16 + lg * 4;
      f32x4 b4 = *(const f32x4*)(bias + co);
      short4v r;
      #pragma unroll
      for (int j = 0; j < 4; ++j) r[j] = (short)f2bf(acc[cot][j] + b4[j] * bscale);
      if (op == 0) {
        *(short4v*)(qb + ((size_t)b * NTOK + n) * CDIM + co) = r;
      } else {
        int colchunk = cot * 2 + (lg >> 1);
        *(short4v*)(ktile + colchunk * 1024 + row * 16 + (lg & 1) * 8) = r;
      }
    }
  }
}

// ------------- kernel 5: flash attention (exact round-8 structure) ----------
// 512 threads = 8 waves x 32 q-cols; lane owns column n = q0 + (lane&31).
// QK^T: S = mfma_32x32x16(K, Q); softmax lane-local; P via cvt_pk +
// permlane32_swap (no LDS P). K,V double-buffered LDS, immediate-offset
// layouts, linear gload_lds staging.
template <bool SPLIT>
__global__ __launch_bounds__(512, 2) void flash_k(const u16* qb, const u16* kb,
                                                  const u16* vb, u16* opart,
                                                  float* ml, u16* ob) {
  int qt = blockIdx.x, b = blockIdx.y, sp = blockIdx.z;
  int tid = threadIdx.x, lane = tid & 63, wid = tid >> 6;
  int ln = lane & 31, hi = lane >> 5;
  __shared__ __align__(16) char k_lds[2][32768];   // [kc 32][m 64][16B]
  __shared__ __align__(16) char v_lds[2][32768];   // [mc 8][c 256][16B]

  int t0 = SPLIT ? 27 * sp : 0;
  int t1 = SPLIT ? 27 * sp + 27 : 108;

  int nq = qt * 256 + wid * 32 + ln;
  const u16* qsrc = qb + ((size_t)b * NTOK + nq) * CDIM;
  short8 qf[16];
  #pragma unroll
  for (int ks = 0; ks < 16; ++ks)
    qf[ks] = *(const short8*)(qsrc + ks * 16 + hi * 8);

  float mrun = -1e30f, lrun = 0.f;
  f32x16 o[8];
  #pragma unroll
  for (int i = 0; i < 8; ++i)
    #pragma unroll
    for (int j = 0; j < 16; ++j) o[i][j] = 0.f;

  const char* kbb = (const char*)(kb + (size_t)b * NTOK * CDIM);
  const char* vbb = (const char*)(vb + (size_t)b * NTOK * CDIM);
  int kbase = hi * 1024 + ln * 16;
  int vbase = hi * 4096 + ln * 16;

  {  // prologue: stage tile t0 into buf 0 (64 x 1KB chunks over 8 waves)
    const char* ks_ = kbb + (size_t)t0 * 32768;
    const char* vs_ = vbb + (size_t)t0 * 32768;
    #pragma unroll
    for (int i = 0; i < 8; ++i) {
      int ch = i * 8 + wid;
      if (ch < 32) gload16(ks_ + ch * 1024 + lane * 16, k_lds[0] + ch * 1024);
      else gload16(vs_ + (ch - 32) * 1024 + lane * 16, v_lds[0] + (ch - 32) * 1024);
    }
  }
  __syncthreads();

  for (int t = t0; t < t1; ++t) {
    int cur = (t - t0) & 1;
    if (t + 1 < t1) {  // prefetch next tile into other buffers
      const char* ks_ = kbb + (size_t)(t + 1) * 32768;
      const char* vs_ = vbb + (size_t)(t + 1) * 32768;
      #pragma unroll
      for (int i = 0; i < 8; ++i) {
        int ch = i * 8 + wid;
        if (ch < 32) gload16(ks_ + ch * 1024 + lane * 16, k_lds[cur ^ 1] + ch * 1024);
        else gload16(vs_ + (ch - 32) * 1024 + lane * 16, v_lds[cur ^ 1] + (ch - 32) * 1024);
      }
    }
    const char* kc = k_lds[cur] + kbase;
    const char* vc = v_lds[cur] + vbase;

    #pragma unroll
    for (int mt = 0; mt < 2; ++mt) {
      // QK^T m-tile: S[m = mt*32 + (r&3)+8*(r>>2)+4*hi][n = lane&31]
      f32x16 S;
      #pragma unroll
      for (int j = 0; j < 16; ++j) S[j] = 0.f;
      __builtin_amdgcn_s_setprio(1);
      #pragma unroll
      for (int ks = 0; ks < 16; ++ks) {
        short8 kf = *(const short8*)(kc + ks * 2048 + mt * 512);
        S = __builtin_amdgcn_mfma_f32_32x32x16_bf16(kf, qf[ks], S, 0, 0, 0);
      }
      __builtin_amdgcn_s_setprio(0);
      // column max: own 16 rows + partner (lane^32)
      float px = S[0];
      #pragma unroll
      for (int j = 1; j < 16; ++j) px = fmaxf(px, S[j]);
      px = fmaxf(px, __shfl_xor(px, 32, 64));
      if (__any(px > mrun + 10.0f)) {   // defer-max; rare after first tile
        float mn = fmaxf(mrun, px);
        float r = exp2f(mrun - mn);
        mrun = mn; lrun *= r;
        #pragma unroll
        for (int i = 0; i < 8; ++i)
          #pragma unroll
          for (int j = 0; j < 16; ++j) o[i][j] *= r;
      }
      float lsum = 0.f;
      #pragma unroll
      for (int j = 0; j < 16; ++j) {
        float p = exp2f(S[j] - mrun);
        S[j] = p; lsum += p;
      }
      lsum += __shfl_xor(lsum, 32, 64);
      lrun += lsum;
      // P pack + PV per local k-step (m = mt*32 + lks*16 + ..)
      #pragma unroll
      for (int lks = 0; lks < 2; ++lks) {
        int rb = lks * 8;
        uint32_t x0, x1, y0, y1;
        asm("v_cvt_pk_bf16_f32 %0, %1, %2" : "=v"(x0) : "v"(S[rb + 0]), "v"(S[rb + 1]));
        asm("v_cvt_pk_bf16_f32 %0, %1, %2" : "=v"(x1) : "v"(S[rb + 2]), "v"(S[rb + 3]));
        asm("v_cvt_pk_bf16_f32 %0, %1, %2" : "=v"(y0) : "v"(S[rb + 4]), "v"(S[rb + 5]));
        asm("v_cvt_pk_bf16_f32 %0, %1, %2" : "=v"(y1) : "v"(S[rb + 6]), "v"(S[rb + 7]));
        // swap vdst upper32 lanes <-> src0 lower32: x' = frag dw0, y' = frag dw2
        asm("v_permlane32_swap_b32 %0, %1" : "+v"(x0), "+v"(y0));
        asm("v_permlane32_swap_b32 %0, %1" : "+v"(x1), "+v"(y1));
        u32x4 pd = (u32x4){x0, x1, y0, y1};
        short8 pf = *(short8*)&pd;
        __builtin_amdgcn_s_setprio(1);
        #pragma unroll
        for (int ct = 0; ct < 8; ++ct) {
          short8 vf = *(const short8*)(vc + (mt * 2 + lks) * 8192 + ct * 512);
          o[ct] = __builtin_amdgcn_mfma_f32_32x32x16_bf16(vf, pf, o[ct], 0, 0, 0);
        }
        __builtin_amdgcn_s_setprio(0);
      }
    }
    __syncthreads();
  }

  // epilogue: lane col n fixed; c = ct*32 + (r&3)+8*(r>>2)+4*hi -> 8B stores
  if (!SPLIT) {
    float linv = 1.0f / lrun;
    u16* d0 = ob + ((size_t)b * NTOK + nq) * CDIM;
    #pragma unroll
    for (int ct = 0; ct < 8; ++ct) {
      #pragma unroll
      for (int rq = 0; rq < 4; ++rq) {
        short4v r4;
        #pragma unroll
        for (int j = 0; j < 4; ++j) r4[j] = (short)f2bf(o[ct][rq * 4 + j] * linv);
        *(short4v*)(d0 + ct * 32 + rq * 8 + hi * 4) = r4;
      }
    }
  } else {
    u16* d0 = opart + ((size_t)(sp * 2 + b) * NTOK + nq) * CDIM;
    #pragma unroll
    for (int ct = 0; ct < 8; ++ct) {
      #pragma unroll
      for (int rq = 0; rq < 4; ++rq) {
        short4v r4;
        #pragma unroll
        for (int j = 0; j < 4; ++j) r4[j] = (short)f2bf(o[ct][rq * 4 + j]);
        *(short4v*)(d0 + ct * 32 + rq * 8 + hi * 4) = r4;
      }
    }
    if (hi == 0) {
      size_t mb = (size_t)(sp * 2 + b) * 2;
      ml[(mb + 0) * NTOK + nq] = mrun;
      ml[(mb + 1) * NTOK + nq] = lrun;
    }
  }
}

// ------------- kernel 6: [combine 4 partials +] proj_out + residual ---------
template <bool SPLIT>
__global__ __launch_bounds__(256) void proj_k(const u16* ob, const u16* opart,
    const float* ml, const u16* wb, const float* bp, const float* x, float* out) {
  int nt = blockIdx.x, b = blockIdx.y;
  int tid = threadIdx.x, lane = tid & 63, wid = tid >> 6;
  int lr = lane & 15, lg = lane >> 4;
  __shared__ __align__(16) char o_lds[32768];   // [64 n][256 c] swizzled
  const u16* wpb = wb + 3 * 65536;
  if (SPLIT) {
    #pragma unroll
    for (int i = 0; i < 8; ++i) {
      int off = i * 4096 + tid * 16;
      int row = off >> 9;
      int c0 = (off & 511) >> 1;
      int n = nt * 64 + row;
      float mm[4], llv[4];
      #pragma unroll
      for (int s = 0; s < 4; ++s) {
        mm[s] = ml[((size_t)(s * 2 + b) * 2 + 0) * NTOK + n];
        llv[s] = ml[((size_t)(s * 2 + b) * 2 + 1) * NTOK + n];
      }
      float M = fmaxf(fmaxf(mm[0], mm[1]), fmaxf(mm[2], mm[3]));
      float w[4]; float den = 0.f;
      #pragma unroll
      for (int s = 0; s < 4; ++s) { w[s] = exp2f(mm[s] - M); den += w[s] * llv[s]; }
      float inv = 1.f / den;
      float o[8] = {0.f, 0.f, 0.f, 0.f, 0.f, 0.f, 0.f, 0.f};
      #pragma unroll
      for (int s = 0; s < 4; ++s) {
        short8 v = *(const short8*)(opart + ((size_t)(s * 2 + b) * NTOK + n) * CDIM + c0);
        #pragma unroll
        for (int j = 0; j < 8; ++j) o[j] += w[s] * bf2f((u16)v[j]);
      }
      short8 r8;
      #pragma unroll
      for (int j = 0; j < 8; ++j) r8[j] = (short)f2bf(o[j] * inv);
      *(short8*)(o_lds + (off ^ ((row & 7) << 4))) = r8;
    }
  } else {
    const char* src = (const char*)(ob + ((size_t)b * NTOK + nt * 64) * CDIM);
    #pragma unroll
    for (int i = 0; i < 8; ++i) {
      int off = i * 4096 + wid * 1024 + lane * 16;
      int row = off >> 9;
      gload16(src + (off ^ ((row & 7) << 4)), o_lds + i * 4096 + wid * 1024);
    }
  }
  __syncthreads();
  #pragma unroll
  for (int ct2 = 0; ct2 < 4; ++ct2) {
    int cot = wid * 4 + ct2;
    short8 aw[8];
    #pragma unroll
    for (int kc = 0; kc < 8; ++kc)
      aw[kc] = *(const short8*)(wpb + (size_t)(cot * 16 + lr) * CDIM + kc * 32 + lg * 8);
    #pragma unroll
    for (int ntile = 0; ntile < 4; ++ntile) {
      f32x4 a = (f32x4){0.f, 0.f, 0.f, 0.f};
      #pragma unroll
      for (int kc = 0; kc < 8; ++kc) {
        int row = ntile * 16 + lr;
        int byte = row * 512 + (kc * 32 + lg * 8) * 2;
        short8 bfr = *(const short8*)(o_lds + (byte ^ ((row & 7) << 4)));
        a = __builtin_amdgcn_mfma_f32_16x16x32_bf16(aw[kc], bfr, a, 0, 0, 0);
      }
      int n = nt * 64 + ntile * 16 + lr;
      int f = n / HW; int hw = n - f * HW;
      #pragma unroll
      for (int j = 0; j < 4; ++j) {
        int co = cot * 16 + lg * 4 + j;
        float val = a[j] + bp[co];
        size_t oi = ((size_t)(b * FR + f) * CDIM + co) * HW + hw;
        out[oi] = x[oi] + val;
      }
    }
  }
}

extern "C" void kernel_launch(void* const* d_in, const int* in_sizes, int n_in,
                              void* d_out, int out_size, void* d_ws, size_t ws_size,
                              hipStream_t stream) {
  const float* x    = (const float*)d_in[0];
  const float* gn_w = (const float*)d_in[1];
  const float* gn_b = (const float*)d_in[2];
  const float* wq   = (const float*)d_in[3];
  const float* bq   = (const float*)d_in[4];
  const float* wk   = (const float*)d_in[5];
  const float* bk   = (const float*)d_in[6];
  const float* wv   = (const float*)d_in[7];
  const float* bv   = (const float*)d_in[8];
  const float* wp   = (const float*)d_in[9];
  const float* bp   = (const float*)d_in[10];
  float* out = (float*)d_out;
  char* ws = (char*)d_ws;

  float* stats = (float*)(ws + 0);          // 16 f32
  float* part  = (float*)(ws + 256);        // 512 f32
  u16* wb = (u16*)(ws + 4096);              // 4*256*256
  u16* hn = (u16*)(ws + 528384);            // [2][6912][256]
  u16* qb = (u16*)(ws + 7606272);
  u16* kb = (u16*)(ws + 14684160);          // [b][tile][colchunk][row][8]
  u16* vb = (u16*)(ws + 21762048);          // [b][tile][mchunk][c][8]
  u16* ob = (u16*)(ws + 28839936);
  u16* opart = (u16*)(ws + 35917824);       // [4 sp][2 b][6912 n][256 c] bf16
  float* ml  = (float*)(ws + 64229376);     // [4 sp][2 b][2][6912] f32
  const size_t NEED_SPLIT = 64671744;

  pre_k<<<512, 256, 0, stream>>>(x, part, wq, wk, wv, wp, wb);
  gn_fin_k<<<1, 64, 0, stream>>>(part, stats);
  gn_apply_k<<<dim3(108, 4, 2), 256, 0, stream>>>(x, gn_w, gn_b, stats, hn);
  qkv_k<<<dim3(108, 6), 256, 0, stream>>>(hn, wb, bq, bk, bv, qb, kb, vb);
  if (ws_size >= NEED_SPLIT) {
    flash_k<true><<<dim3(27, 2, 4), 512, 0, stream>>>(qb, kb, vb, opart, ml, ob);
    proj_k<true><<<dim3(108, 2), 256, 0, stream>>>(ob, opart, ml, wb, bp, x, out);
  } else {
    flash_k<false><<<dim3(27, 2, 1), 512, 0, stream>>>(qb, kb, vb, opart, ml, ob);
    proj_k<false><<<dim3(108, 2), 256, 0, stream>>>(ob, opart, ml, wb, bp, x, out);
  }
}